// Round 14
// baseline (138.977 us; speedup 1.0000x reference)
//
#include <hip/hip_runtime.h>

// SparseMoE: T=4096, D=1024, E=8, H=2048, top_k=2.
// R14: R8's proven K-loop untouched. Changes around it:
//  (1) compact self-locating grid (1152 blocks; each prefix-scans counts[8]
//      to decode e/rb/cb) -> no 3072 dead-block churn, one concurrent round,
//      cb-fastest order so 16 consecutive blocks share the gathered A-tile;
//  (2) __launch_bounds__(256,4) -> up to 4 blocks/CU overlap the drains;
//  (3) convert_eW fused with gate (block-range split) -> concurrent
//      memory-bound prologue, one less launch gap.

#define NTOK 4096
#define DIM  1024
#define NEXP 8
#define HID  2048

#define BM 128
#define BN 128
#define BK 64

#define CONV_BLOCKS 8192   // eW elems / (256*8)
#define MAXTILES 1152      // worst-case live tiles: (64+8) rb * 16 cb

using u16    = unsigned short;
using u16x4  = __attribute__((ext_vector_type(4))) unsigned short;
using u16x8  = __attribute__((ext_vector_type(8))) unsigned short;
using bf16x8 = __attribute__((ext_vector_type(8))) __bf16;
using f32x4  = __attribute__((ext_vector_type(4))) float;

typedef const __attribute__((address_space(1))) unsigned char* gas1p;
typedef __attribute__((address_space(3))) unsigned char* gas3p;

__device__ __forceinline__ void gload16(void* lds, const void* g) {
  __builtin_amdgcn_global_load_lds((gas1p)g, (gas3p)lds, 16, 0, 0);
}

__device__ inline u16 f2bf(float f) {
  union { float f; unsigned u; } v; v.f = f;
  unsigned r = v.u + 0x7fffu + ((v.u >> 16) & 1u);  // RNE, no NaN in this data
  return (u16)(r >> 16);
}
__device__ inline float bf2f(u16 b) {
  union { unsigned u; float f; } v; v.u = ((unsigned)b) << 16; return v.f;
}

// ------ fused prologue: blocks [0,8192) convert eW->bf16; rest do gating -----
__global__ __launch_bounds__(256) void pre_kernel(
    const float* __restrict__ eW, u16* __restrict__ wbf,
    const float* __restrict__ x, const float* __restrict__ gW,
    const float* __restrict__ gb, float* __restrict__ probs,
    int* __restrict__ top2, u16* __restrict__ xbf) {
  if (blockIdx.x < CONV_BLOCKS) {
    // ---- eW fp32 -> bf16, 8 elems/thread ----
    int i = blockIdx.x * 256 + threadIdx.x;
    const float4* p = (const float4*)eW + (size_t)i * 2;
    float4 a = p[0], b = p[1];
    u16x8 r;
    r[0] = f2bf(a.x); r[1] = f2bf(a.y); r[2] = f2bf(a.z); r[3] = f2bf(a.w);
    r[4] = f2bf(b.x); r[5] = f2bf(b.y); r[6] = f2bf(b.z); r[7] = f2bf(b.w);
    *((u16x8*)wbf + i) = r;
    return;
  }

  // ---- gating: fp64 logits, softmax, top-2; also emits xbf ----
  const int wave = threadIdx.x >> 6;
  const int lane = threadIdx.x & 63;
  const int t = (blockIdx.x - CONV_BLOCKS) * 4 + wave;

  const float4* xrow = (const float4*)(x + (size_t)t * DIM);
  double acc[NEXP];
#pragma unroll
  for (int e = 0; e < NEXP; ++e) acc[e] = 0.0;

#pragma unroll
  for (int c = 0; c < 4; ++c) {
    int idx = c * 64 + lane;          // float4 index; elems 4*idx..4*idx+3
    float4 xv = xrow[idx];
    u16x4 bv;
    bv[0] = f2bf(xv.x); bv[1] = f2bf(xv.y); bv[2] = f2bf(xv.z); bv[3] = f2bf(xv.w);
    *(u16x4*)(xbf + (size_t)t * DIM + 4 * idx) = bv;   // fused convert_x
#pragma unroll
    for (int e = 0; e < NEXP; ++e) {
      float4 wv = ((const float4*)(gW + (size_t)e * DIM))[idx];
      acc[e] += (double)xv.x * wv.x + (double)xv.y * wv.y +
                (double)xv.z * wv.z + (double)xv.w * wv.w;
    }
  }
#pragma unroll
  for (int e = 0; e < NEXP; ++e) {
    double v = acc[e];
#pragma unroll
    for (int off = 32; off > 0; off >>= 1) v += __shfl_down(v, off);
    acc[e] = v;
  }

  if (lane == 0) {
    double logits[NEXP];
#pragma unroll
    for (int e = 0; e < NEXP; ++e) logits[e] = acc[e] + (double)gb[e];
    double m = logits[0];
#pragma unroll
    for (int e = 1; e < NEXP; ++e) m = fmax(m, logits[e]);
    double p[NEXP], s = 0.0;
#pragma unroll
    for (int e = 0; e < NEXP; ++e) { p[e] = exp(logits[e] - m); s += p[e]; }
#pragma unroll
    for (int e = 0; e < NEXP; ++e) p[e] /= s;

    int i1 = 0;
#pragma unroll
    for (int e = 1; e < NEXP; ++e) if (p[e] > p[i1]) i1 = e;
    int i2 = (i1 == 0) ? 1 : 0;
#pragma unroll
    for (int e = 0; e < NEXP; ++e) {
      if (e != i1 && p[e] > p[i2]) i2 = e;
    }

#pragma unroll
    for (int e = 0; e < NEXP; ++e) probs[(size_t)t * NEXP + e] = (float)p[e];
    top2[t] = i1 | (i2 << 4);
  }
}

// ------- route: per-expert stable compaction (ballot prefix) + fp64 variance -
__global__ __launch_bounds__(256) void route_kernel(
    const float* __restrict__ probs, const int* __restrict__ top2,
    int* __restrict__ counts, int* __restrict__ lists,
    float* __restrict__ var_out) {
  const int e = blockIdx.x;
  const int tid = threadIdx.x;
  const int lane = tid & 63;
  const int wave = tid >> 6;

  __shared__ int wsum[4];
  __shared__ double ds[4], dq[4];

  double s = 0.0, q = 0.0;
  int base = 0;

  for (int c = 0; c < NTOK / 256; ++c) {
    int t = c * 256 + tid;
    float p = probs[(size_t)t * NEXP + e];
    s += (double)p;
    q += (double)p * (double)p;

    int m = top2[t];
    bool f = ((m & 15) == e) || (((m >> 4) & 15) == e);
    unsigned long long bal = __ballot(f);
    int before = __popcll(bal & ((1ull << lane) - 1ull));
    if (lane == 0) wsum[wave] = __popcll(bal);
    __syncthreads();
    int woff = 0;
#pragma unroll
    for (int w = 0; w < 4; ++w) if (w < wave) woff += wsum[w];
    int ctotal = wsum[0] + wsum[1] + wsum[2] + wsum[3];
    if (f) lists[e * NTOK + base + woff + before] = t;
    base += ctotal;
    __syncthreads();
  }
  if (tid == 0) counts[e] = base;

#pragma unroll
  for (int off = 32; off > 0; off >>= 1) {
    s += __shfl_down(s, off);
    q += __shfl_down(q, off);
  }
  if (lane == 0) { ds[wave] = s; dq[wave] = q; }
  __syncthreads();
  if (tid == 0) {
    double S = ds[0] + ds[1] + ds[2] + ds[3];
    double Q = dq[0] + dq[1] + dq[2] + dq[3];
    var_out[e] = (float)((Q - S * S / (double)NTOK) / (double)(NTOK - 1));
  }
}

// --- gathered expert GEMM: R8 K-loop, compact self-locating grid, 4 blk/CU ---
// Block decodes (e, rb, cb) by prefix-scanning counts[8]; only live tiles
// exist (<=128 pad blocks exit). cb-fastest: 16 consecutive blocks share the
// A-tile. LDS tile (A and B): [128 rows][64 cols] bf16, 16B-chunk swizzle
// stored_c16 = c16 ^ (row&7); global_load_lds writes linearly, source carries
// the inverse XOR. Epilogue: bf16 partial stores to pbf[k][token][h].
__global__ __launch_bounds__(256, 4) void expert_gemm(
    const u16* __restrict__ xbf, const u16* __restrict__ wbf,
    const int* __restrict__ counts, const int* __restrict__ lists,
    const int* __restrict__ top2, u16* __restrict__ pbf) {
  __shared__ u16 As[BM * BK];   // 16 KB
  __shared__ u16 Bs[BN * BK];   // 16 KB
  __shared__ int tok[BM];
  __shared__ int kslot[BM];

  // ---- self-locate: prefix-scan counts to find (e, rb, cb) ----
  int rem = blockIdx.x;
  int e = 0, cnt = 0;
#pragma unroll
  for (int ee = 0; ee < NEXP; ++ee) {
    int c = counts[ee];
    int nt = ((c + BM - 1) >> 7) << 4;   // live rb-tiles * 16 cb
    if (e == ee) {
      if (rem < nt) { cnt = c; }
      else { rem -= nt; e = ee + 1; }
    }
  }
  if (e >= NEXP) return;                  // pad block
  cnt = counts[e];
  const int rb = rem >> 4;                // cb-fastest
  const int cb = rem & 15;

  const int tid  = threadIdx.x;
  const int wave = tid >> 6;
  const int lane = tid & 63;

  if (tid < BM) {
    int gi = rb * BM + tid;
    int tr = (gi < cnt) ? lists[e * NTOK + gi] : -1;
    tok[tid] = tr;
    kslot[tid] = (tr >= 0 && (top2[tr] & 15) == e) ? 0 : 1;
  }
  __syncthreads();

  // ---- staging precompute: 4 A-issues + 4 B-issues of 16B per thread ----
  const u16* asrc[4];
  const u16* bsrc[4];
  int ldsoff[4];
#pragma unroll
  for (int j = 0; j < 4; ++j) {
    const int idx  = (j * 4 + wave) * 64 + lane;  // 16B-chunk index in [0,1024)
    const int row  = idx >> 3;
    const int c16  = (idx & 7) ^ (row & 7);       // inverse swizzle on source
    int tr = tok[row]; if (tr < 0) tr = 0;        // clamped; row discarded later
    asrc[j] = xbf + (size_t)tr * DIM + c16 * 8;
    bsrc[j] = wbf + ((size_t)e * HID + (size_t)cb * BN + row) * DIM + c16 * 8;
    ldsoff[j] = (j * 4 + wave) * 512;             // wave-uniform base
  }

  const int wm = (wave >> 1) * 64;
  const int wn = (wave & 1) * 64;
  const int lr = lane & 15;
  const int hk = lane >> 4;        // k-group 0..3

  f32x4 acc[4][4];
#pragma unroll
  for (int m = 0; m < 4; ++m)
#pragma unroll
    for (int n = 0; n < 4; ++n) acc[m][n] = (f32x4)(0.0f);

  for (int k0 = 0; k0 < DIM; k0 += BK) {
#pragma unroll
    for (int j = 0; j < 4; ++j) gload16(&As[ldsoff[j]], asrc[j] + k0);
#pragma unroll
    for (int j = 0; j < 4; ++j) gload16(&Bs[ldsoff[j]], bsrc[j] + k0);

    __syncthreads();   // vmcnt(0) drain + barrier

    bf16x8 fa[2][4], fb[2][4];
#pragma unroll
    for (int kk = 0; kk < 2; ++kk) {
#pragma unroll
      for (int m = 0; m < 4; ++m) {
        const int row = wm + m * 16 + lr;
        const int c16 = (kk * 4 + hk) ^ (row & 7);
        fa[kk][m] = *(const bf16x8*)&As[row * 64 + c16 * 8];
      }
#pragma unroll
      for (int n = 0; n < 4; ++n) {
        const int row = wn + n * 16 + lr;
        const int c16 = (kk * 4 + hk) ^ (row & 7);
        fb[kk][n] = *(const bf16x8*)&Bs[row * 64 + c16 * 8];
      }
    }

#pragma unroll
    for (int kk = 0; kk < 2; ++kk)
#pragma unroll
      for (int m = 0; m < 4; ++m)
#pragma unroll
        for (int n = 0; n < 4; ++n)
          acc[m][n] = __builtin_amdgcn_mfma_f32_16x16x32_bf16(
              fa[kk][m], fb[kk][n], acc[m][n], 0, 0, 0);

    __syncthreads();
  }

  // ---- epilogue: plain bf16 partial stores (deterministic, no atomics) ----
#pragma unroll
  for (int n = 0; n < 4; ++n) {
    const int hcol = cb * BN + wn + n * 16 + lr;
#pragma unroll
    for (int m = 0; m < 4; ++m) {
#pragma unroll
      for (int i = 0; i < 4; ++i) {
        int rloc = wm + m * 16 + hk * 4 + i;   // C/D: row=(lane>>4)*4+i
        int tr = tok[rloc];
        if (tr >= 0)
          pbf[((size_t)kslot[rloc] * NTOK + tr) * HID + hcol] =
              f2bf(acc[m][n][i]);
      }
    }
  }
}

// ---- combine: out[t] = 0.5*(p0 + p1 + b_e1 + b_e2); fully memory-bound -----
__global__ __launch_bounds__(256) void combine_kernel(
    const u16* __restrict__ pbf, const int* __restrict__ top2,
    const float* __restrict__ eb, float* __restrict__ out) {
  const int t = blockIdx.x;
  const int h = threadIdx.x * 8;
  const int m2 = top2[t];
  const int e1 = m2 & 15, e2 = (m2 >> 4) & 15;

  u16x8 p0 = *(const u16x8*)&pbf[(size_t)t * HID + h];
  u16x8 p1 = *(const u16x8*)&pbf[((size_t)NTOK + t) * HID + h];
  const float4* b1 = (const float4*)&eb[e1 * HID + h];
  const float4* b2 = (const float4*)&eb[e2 * HID + h];
  float4 b1a = b1[0], b1b = b1[1], b2a = b2[0], b2b = b2[1];

  float4 o0, o1;
  o0.x = 0.5f * (bf2f(p0[0]) + bf2f(p1[0]) + b1a.x + b2a.x);
  o0.y = 0.5f * (bf2f(p0[1]) + bf2f(p1[1]) + b1a.y + b2a.y);
  o0.z = 0.5f * (bf2f(p0[2]) + bf2f(p1[2]) + b1a.z + b2a.z);
  o0.w = 0.5f * (bf2f(p0[3]) + bf2f(p1[3]) + b1a.w + b2a.w);
  o1.x = 0.5f * (bf2f(p0[4]) + bf2f(p1[4]) + b1b.x + b2b.x);
  o1.y = 0.5f * (bf2f(p0[5]) + bf2f(p1[5]) + b1b.y + b2b.y);
  o1.z = 0.5f * (bf2f(p0[6]) + bf2f(p1[6]) + b1b.z + b2b.z);
  o1.w = 0.5f * (bf2f(p0[7]) + bf2f(p1[7]) + b1b.w + b2b.w);

  float4* po = (float4*)&out[(size_t)t * HID + h];
  po[0] = o0; po[1] = o1;
}

extern "C" void kernel_launch(void* const* d_in, const int* in_sizes, int n_in,
                              void* d_out, int out_size, void* d_ws, size_t ws_size,
                              hipStream_t stream) {
  const float* x  = (const float*)d_in[0];   // [4096,1024]
  const float* gW = (const float*)d_in[1];   // [8,1024]
  const float* gb = (const float*)d_in[2];   // [8]
  const float* eW = (const float*)d_in[3];   // [8,2048,1024]
  const float* eb = (const float*)d_in[4];   // [8,2048]

  float* out = (float*)d_out;
  float* var_out = out + (size_t)NTOK * HID;

  // ws layout
  char* ws = (char*)d_ws;
  int*   counts = (int*)ws;                                   // 32 B
  int*   lists  = (int*)(ws + 1024);                          // 128 KB
  float* probs  = (float*)(ws + 1024 + 131072);               // 128 KB
  int*   top2   = (int*)(ws + 1024 + 2 * 131072);             // 16 KB
  u16*   xbf    = (u16*)(ws + 294912);                        // 8 MB
  u16*   wbf    = (u16*)((char*)xbf + (size_t)NTOK * DIM * 2);// 32 MB
  u16*   pbf    = (u16*)((char*)wbf + (size_t)NEXP * HID * DIM * 2);  // 32 MB

  pre_kernel<<<CONV_BLOCKS + NTOK / 4, 256, 0, stream>>>(
      eW, wbf, x, gW, gb, probs, top2, xbf);
  route_kernel<<<NEXP, 256, 0, stream>>>(probs, top2, counts, lists, var_out);
  expert_gemm<<<MAXTILES, 256, 0, stream>>>(
      xbf, wbf, counts, lists, top2, pbf);
  combine_kernel<<<NTOK, 256, 0, stream>>>(pbf, top2, eb, out);
}

// Round 15
// 106.897 us; speedup vs baseline: 1.3001x; 1.3001x over previous
//
#include <hip/hip_runtime.h>

// SparseMoE: T=4096, D=1024, E=8, H=2048, top_k=2.
// R15: best-known assembly. expert_gemm = R8 byte-for-byte (the 70us config:
// 4096-block grid incl. dead blocks -- their dispatch interleave staggers
// staging bursts; launch_bounds(256,2); BK=64 single-buffer 33KB; swizzled
// global_load_lds; bf16 partial epilogue, no atomics). Prologue = R14's
// fused pre_kernel (convert_eW || gate, -5us). route + combine unchanged.
// Falsified this session: dbuf (R4/R10/R13), big tiles (R5/R12), persistent
// (R7), compact grid (R14), 4 blk/CU (R9/R14), XCD locality (R9/R11).

#define NTOK 4096
#define DIM  1024
#define NEXP 8
#define HID  2048

#define BM 128
#define BN 128
#define BK 64

#define CONV_BLOCKS 8192   // eW elems / (256*8)

using u16    = unsigned short;
using u16x4  = __attribute__((ext_vector_type(4))) unsigned short;
using u16x8  = __attribute__((ext_vector_type(8))) unsigned short;
using bf16x8 = __attribute__((ext_vector_type(8))) __bf16;
using f32x4  = __attribute__((ext_vector_type(4))) float;

typedef const __attribute__((address_space(1))) unsigned char* gas1p;
typedef __attribute__((address_space(3))) unsigned char* gas3p;

__device__ __forceinline__ void gload16(void* lds, const void* g) {
  __builtin_amdgcn_global_load_lds((gas1p)g, (gas3p)lds, 16, 0, 0);
}

__device__ inline u16 f2bf(float f) {
  union { float f; unsigned u; } v; v.f = f;
  unsigned r = v.u + 0x7fffu + ((v.u >> 16) & 1u);  // RNE, no NaN in this data
  return (u16)(r >> 16);
}
__device__ inline float bf2f(u16 b) {
  union { unsigned u; float f; } v; v.u = ((unsigned)b) << 16; return v.f;
}

// ------ fused prologue: blocks [0,8192) convert eW->bf16; rest do gating -----
__global__ __launch_bounds__(256) void pre_kernel(
    const float* __restrict__ eW, u16* __restrict__ wbf,
    const float* __restrict__ x, const float* __restrict__ gW,
    const float* __restrict__ gb, float* __restrict__ probs,
    int* __restrict__ top2, u16* __restrict__ xbf) {
  if (blockIdx.x < CONV_BLOCKS) {
    int i = blockIdx.x * 256 + threadIdx.x;
    const float4* p = (const float4*)eW + (size_t)i * 2;
    float4 a = p[0], b = p[1];
    u16x8 r;
    r[0] = f2bf(a.x); r[1] = f2bf(a.y); r[2] = f2bf(a.z); r[3] = f2bf(a.w);
    r[4] = f2bf(b.x); r[5] = f2bf(b.y); r[6] = f2bf(b.z); r[7] = f2bf(b.w);
    *((u16x8*)wbf + i) = r;
    return;
  }

  // ---- gating: fp64 logits, softmax, top-2; also emits xbf ----
  const int wave = threadIdx.x >> 6;
  const int lane = threadIdx.x & 63;
  const int t = (blockIdx.x - CONV_BLOCKS) * 4 + wave;

  const float4* xrow = (const float4*)(x + (size_t)t * DIM);
  double acc[NEXP];
#pragma unroll
  for (int e = 0; e < NEXP; ++e) acc[e] = 0.0;

#pragma unroll
  for (int c = 0; c < 4; ++c) {
    int idx = c * 64 + lane;          // float4 index; elems 4*idx..4*idx+3
    float4 xv = xrow[idx];
    u16x4 bv;
    bv[0] = f2bf(xv.x); bv[1] = f2bf(xv.y); bv[2] = f2bf(xv.z); bv[3] = f2bf(xv.w);
    *(u16x4*)(xbf + (size_t)t * DIM + 4 * idx) = bv;   // fused convert_x
#pragma unroll
    for (int e = 0; e < NEXP; ++e) {
      float4 wv = ((const float4*)(gW + (size_t)e * DIM))[idx];
      acc[e] += (double)xv.x * wv.x + (double)xv.y * wv.y +
                (double)xv.z * wv.z + (double)xv.w * wv.w;
    }
  }
#pragma unroll
  for (int e = 0; e < NEXP; ++e) {
    double v = acc[e];
#pragma unroll
    for (int off = 32; off > 0; off >>= 1) v += __shfl_down(v, off);
    acc[e] = v;
  }

  if (lane == 0) {
    double logits[NEXP];
#pragma unroll
    for (int e = 0; e < NEXP; ++e) logits[e] = acc[e] + (double)gb[e];
    double m = logits[0];
#pragma unroll
    for (int e = 1; e < NEXP; ++e) m = fmax(m, logits[e]);
    double p[NEXP], s = 0.0;
#pragma unroll
    for (int e = 0; e < NEXP; ++e) { p[e] = exp(logits[e] - m); s += p[e]; }
#pragma unroll
    for (int e = 0; e < NEXP; ++e) p[e] /= s;

    int i1 = 0;
#pragma unroll
    for (int e = 1; e < NEXP; ++e) if (p[e] > p[i1]) i1 = e;
    int i2 = (i1 == 0) ? 1 : 0;
#pragma unroll
    for (int e = 0; e < NEXP; ++e) {
      if (e != i1 && p[e] > p[i2]) i2 = e;
    }

#pragma unroll
    for (int e = 0; e < NEXP; ++e) probs[(size_t)t * NEXP + e] = (float)p[e];
    top2[t] = i1 | (i2 << 4);
  }
}

// ------- route: per-expert stable compaction (ballot prefix) + fp64 variance -
__global__ __launch_bounds__(256) void route_kernel(
    const float* __restrict__ probs, const int* __restrict__ top2,
    int* __restrict__ counts, int* __restrict__ lists,
    float* __restrict__ var_out) {
  const int e = blockIdx.x;
  const int tid = threadIdx.x;
  const int lane = tid & 63;
  const int wave = tid >> 6;

  __shared__ int wsum[4];
  __shared__ double ds[4], dq[4];

  double s = 0.0, q = 0.0;
  int base = 0;

  for (int c = 0; c < NTOK / 256; ++c) {
    int t = c * 256 + tid;
    float p = probs[(size_t)t * NEXP + e];
    s += (double)p;
    q += (double)p * (double)p;

    int m = top2[t];
    bool f = ((m & 15) == e) || (((m >> 4) & 15) == e);
    unsigned long long bal = __ballot(f);
    int before = __popcll(bal & ((1ull << lane) - 1ull));
    if (lane == 0) wsum[wave] = __popcll(bal);
    __syncthreads();
    int woff = 0;
#pragma unroll
    for (int w = 0; w < 4; ++w) if (w < wave) woff += wsum[w];
    int ctotal = wsum[0] + wsum[1] + wsum[2] + wsum[3];
    if (f) lists[e * NTOK + base + woff + before] = t;
    base += ctotal;
    __syncthreads();
  }
  if (tid == 0) counts[e] = base;

#pragma unroll
  for (int off = 32; off > 0; off >>= 1) {
    s += __shfl_down(s, off);
    q += __shfl_down(q, off);
  }
  if (lane == 0) { ds[wave] = s; dq[wave] = q; }
  __syncthreads();
  if (tid == 0) {
    double S = ds[0] + ds[1] + ds[2] + ds[3];
    double Q = dq[0] + dq[1] + dq[2] + dq[3];
    var_out[e] = (float)((Q - S * S / (double)NTOK) / (double)(NTOK - 1));
  }
}

// --------- gathered expert GEMM: R8 exact (the measured 70us config) ---------
// LDS tile (A and B): logical [128 rows][64 cols] bf16 row-major, 16B-chunk
// swizzle stored_c16 = c16 ^ (row&7). global_load_lds writes LDS linearly;
// global source carries the inverse (same) XOR. Epilogue: plain bf16 stores
// to partial[k][token][h], k = slot of expert e in token's top2.
__global__ __launch_bounds__(256, 2) void expert_gemm(
    const u16* __restrict__ xbf, const u16* __restrict__ wbf,
    const int* __restrict__ counts, const int* __restrict__ lists,
    const int* __restrict__ top2, u16* __restrict__ pbf) {
  __shared__ u16 As[BM * BK];   // 16 KB
  __shared__ u16 Bs[BN * BK];   // 16 KB
  __shared__ int tok[BM];
  __shared__ int kslot[BM];

  const int bid = blockIdx.x;
  const int e  = bid >> 9;          // 512 blocks/expert: 32 rb x 16 cb
  const int rb = (bid >> 4) & 31;
  const int cb = bid & 15;
  const int cnt = counts[e];
  if (rb * BM >= cnt) return;

  const int tid  = threadIdx.x;
  const int wave = tid >> 6;
  const int lane = tid & 63;

  if (tid < BM) {
    int gi = rb * BM + tid;
    int tr = (gi < cnt) ? lists[e * NTOK + gi] : -1;
    tok[tid] = tr;
    kslot[tid] = (tr >= 0 && (top2[tr] & 15) == e) ? 0 : 1;
  }
  __syncthreads();

  // ---- staging precompute: 4 A-issues + 4 B-issues of 16B per thread ----
  const u16* asrc[4];
  const u16* bsrc[4];
  int ldsoff[4];
#pragma unroll
  for (int j = 0; j < 4; ++j) {
    const int idx  = (j * 4 + wave) * 64 + lane;  // 16B-chunk index in [0,1024)
    const int row  = idx >> 3;
    const int c16  = (idx & 7) ^ (row & 7);       // inverse swizzle on source
    int tr = tok[row]; if (tr < 0) tr = 0;        // clamped; row discarded later
    asrc[j] = xbf + (size_t)tr * DIM + c16 * 8;
    bsrc[j] = wbf + ((size_t)e * HID + (size_t)cb * BN + row) * DIM + c16 * 8;
    ldsoff[j] = (j * 4 + wave) * 512;             // wave-uniform base
  }

  const int wm = (wave >> 1) * 64;
  const int wn = (wave & 1) * 64;
  const int lr = lane & 15;
  const int hk = lane >> 4;        // k-group 0..3

  f32x4 acc[4][4];
#pragma unroll
  for (int m = 0; m < 4; ++m)
#pragma unroll
    for (int n = 0; n < 4; ++n) acc[m][n] = (f32x4)(0.0f);

  for (int k0 = 0; k0 < DIM; k0 += BK) {
#pragma unroll
    for (int j = 0; j < 4; ++j) gload16(&As[ldsoff[j]], asrc[j] + k0);
#pragma unroll
    for (int j = 0; j < 4; ++j) gload16(&Bs[ldsoff[j]], bsrc[j] + k0);

    __syncthreads();   // vmcnt(0) drain + barrier

    bf16x8 fa[2][4], fb[2][4];
#pragma unroll
    for (int kk = 0; kk < 2; ++kk) {
#pragma unroll
      for (int m = 0; m < 4; ++m) {
        const int row = wm + m * 16 + lr;
        const int c16 = (kk * 4 + hk) ^ (row & 7);
        fa[kk][m] = *(const bf16x8*)&As[row * 64 + c16 * 8];
      }
#pragma unroll
      for (int n = 0; n < 4; ++n) {
        const int row = wn + n * 16 + lr;
        const int c16 = (kk * 4 + hk) ^ (row & 7);
        fb[kk][n] = *(const bf16x8*)&Bs[row * 64 + c16 * 8];
      }
    }

#pragma unroll
    for (int kk = 0; kk < 2; ++kk)
#pragma unroll
      for (int m = 0; m < 4; ++m)
#pragma unroll
        for (int n = 0; n < 4; ++n)
          acc[m][n] = __builtin_amdgcn_mfma_f32_16x16x32_bf16(
              fa[kk][m], fb[kk][n], acc[m][n], 0, 0, 0);

    __syncthreads();
  }

  // ---- epilogue: plain bf16 partial stores (deterministic, no atomics) ----
#pragma unroll
  for (int n = 0; n < 4; ++n) {
    const int hcol = cb * BN + wn + n * 16 + lr;
#pragma unroll
    for (int m = 0; m < 4; ++m) {
#pragma unroll
      for (int i = 0; i < 4; ++i) {
        int rloc = wm + m * 16 + hk * 4 + i;   // C/D: row=(lane>>4)*4+i
        int tr = tok[rloc];
        if (tr >= 0)
          pbf[((size_t)kslot[rloc] * NTOK + tr) * HID + hcol] =
              f2bf(acc[m][n][i]);
      }
    }
  }
}

// ---- combine: out[t] = 0.5*(p0 + p1 + b_e1 + b_e2); fully memory-bound -----
__global__ __launch_bounds__(256) void combine_kernel(
    const u16* __restrict__ pbf, const int* __restrict__ top2,
    const float* __restrict__ eb, float* __restrict__ out) {
  const int t = blockIdx.x;
  const int h = threadIdx.x * 8;
  const int m2 = top2[t];
  const int e1 = m2 & 15, e2 = (m2 >> 4) & 15;

  u16x8 p0 = *(const u16x8*)&pbf[(size_t)t * HID + h];
  u16x8 p1 = *(const u16x8*)&pbf[((size_t)NTOK + t) * HID + h];
  const float4* b1 = (const float4*)&eb[e1 * HID + h];
  const float4* b2 = (const float4*)&eb[e2 * HID + h];
  float4 b1a = b1[0], b1b = b1[1], b2a = b2[0], b2b = b2[1];

  float4 o0, o1;
  o0.x = 0.5f * (bf2f(p0[0]) + bf2f(p1[0]) + b1a.x + b2a.x);
  o0.y = 0.5f * (bf2f(p0[1]) + bf2f(p1[1]) + b1a.y + b2a.y);
  o0.z = 0.5f * (bf2f(p0[2]) + bf2f(p1[2]) + b1a.z + b2a.z);
  o0.w = 0.5f * (bf2f(p0[3]) + bf2f(p1[3]) + b1a.w + b2a.w);
  o1.x = 0.5f * (bf2f(p0[4]) + bf2f(p1[4]) + b1b.x + b2b.x);
  o1.y = 0.5f * (bf2f(p0[5]) + bf2f(p1[5]) + b1b.y + b2b.y);
  o1.z = 0.5f * (bf2f(p0[6]) + bf2f(p1[6]) + b1b.z + b2b.z);
  o1.w = 0.5f * (bf2f(p0[7]) + bf2f(p1[7]) + b1b.w + b2b.w);

  float4* po = (float4*)&out[(size_t)t * HID + h];
  po[0] = o0; po[1] = o1;
}

extern "C" void kernel_launch(void* const* d_in, const int* in_sizes, int n_in,
                              void* d_out, int out_size, void* d_ws, size_t ws_size,
                              hipStream_t stream) {
  const float* x  = (const float*)d_in[0];   // [4096,1024]
  const float* gW = (const float*)d_in[1];   // [8,1024]
  const float* gb = (const float*)d_in[2];   // [8]
  const float* eW = (const float*)d_in[3];   // [8,2048,1024]
  const float* eb = (const float*)d_in[4];   // [8,2048]

  float* out = (float*)d_out;
  float* var_out = out + (size_t)NTOK * HID;

  // ws layout
  char* ws = (char*)d_ws;
  int*   counts = (int*)ws;                                   // 32 B
  int*   lists  = (int*)(ws + 1024);                          // 128 KB
  float* probs  = (float*)(ws + 1024 + 131072);               // 128 KB
  int*   top2   = (int*)(ws + 1024 + 2 * 131072);             // 16 KB
  u16*   xbf    = (u16*)(ws + 294912);                        // 8 MB
  u16*   wbf    = (u16*)((char*)xbf + (size_t)NTOK * DIM * 2);// 32 MB
  u16*   pbf    = (u16*)((char*)wbf + (size_t)NEXP * HID * DIM * 2);  // 32 MB

  pre_kernel<<<CONV_BLOCKS + NTOK / 4, 256, 0, stream>>>(
      eW, wbf, x, gW, gb, probs, top2, xbf);
  route_kernel<<<NEXP, 256, 0, stream>>>(probs, top2, counts, lists, var_out);
  expert_gemm<<<NEXP * (NTOK / BM) * (HID / BN), 256, 0, stream>>>(
      xbf, wbf, counts, lists, top2, pbf);
  combine_kernel<<<NTOK, 256, 0, stream>>>(pbf, top2, eb, out);
}